// Round 1
// baseline (75.664 us; speedup 1.0000x reference)
//
#include <hip/hip_runtime.h>

// Problem constants (from reference): B=8, M=64, N=64, P=3, Q=3, GRID=512, DIM=3
#define GRID_PTS 512
#define M_CTRL   64
#define N_CTRL   64

// One block per (b, g) row. Stage-1: 64 lanes compute Su[n] (u-direction
// contraction) into LDS. Stage-2: 128 threads each produce 4 consecutive h
// points (v-direction contraction + perspective divide) and store 48 B as
// three float4's (aligned: row base is 6144 B-aligned, thread offset 48t).
__global__ __launch_bounds__(128) void surfeval_kernel(
    const float4* __restrict__ ctrl,   // (B, M, N) of float4 (xyz*w, w)
    const int*    __restrict__ uspan,  // (GRID)
    const int*    __restrict__ vspan,  // (GRID)
    const float4* __restrict__ Nu,     // (GRID) basis coeffs, 4 per g
    const float4* __restrict__ Nv,     // (GRID)
    float*        __restrict__ out)    // (B, GRID, GRID, 3)
{
    __shared__ float4 Su[N_CTRL];

    const int blk = blockIdx.x;            // b*GRID + g
    const int g   = blk & (GRID_PTS - 1);
    const int b   = blk >> 9;
    const int t   = threadIdx.x;

    // ---- Stage 1: Su[n] = sum_r Nu[g][r] * ctrl[b][uspan[g]-3+r][n] ----
    if (t < N_CTRL) {
        const int    iu = uspan[g] - 3;
        const float4 nu = Nu[g];
        const float4* cp = ctrl + ((size_t)b * M_CTRL + iu) * N_CTRL + t;
        const float4 c0 = cp[0 * N_CTRL];
        const float4 c1 = cp[1 * N_CTRL];
        const float4 c2 = cp[2 * N_CTRL];
        const float4 c3 = cp[3 * N_CTRL];
        float4 s;
        s.x = nu.x * c0.x + nu.y * c1.x + nu.z * c2.x + nu.w * c3.x;
        s.y = nu.x * c0.y + nu.y * c1.y + nu.z * c2.y + nu.w * c3.y;
        s.z = nu.x * c0.z + nu.y * c1.z + nu.z * c2.z + nu.w * c3.z;
        s.w = nu.x * c0.w + nu.y * c1.w + nu.z * c2.w + nu.w * c3.w;
        Su[t] = s;
    }
    __syncthreads();

    // ---- Stage 2: 4 h-points per thread ----
    const int h0 = t * 4;
    float r[12];
#pragma unroll
    for (int i = 0; i < 4; ++i) {
        const int    h  = h0 + i;
        const int    iv = vspan[h] - 3;
        const float4 nv = Nv[h];
        const float4 a0 = Su[iv + 0];
        const float4 a1 = Su[iv + 1];
        const float4 a2 = Su[iv + 2];
        const float4 a3 = Su[iv + 3];
        const float sx = nv.x * a0.x + nv.y * a1.x + nv.z * a2.x + nv.w * a3.x;
        const float sy = nv.x * a0.y + nv.y * a1.y + nv.z * a2.y + nv.w * a3.y;
        const float sz = nv.x * a0.z + nv.y * a1.z + nv.z * a2.z + nv.w * a3.z;
        const float sw = nv.x * a0.w + nv.y * a1.w + nv.z * a2.w + nv.w * a3.w;
        const float inv = 1.0f / sw;
        r[i * 3 + 0] = sx * inv;
        r[i * 3 + 1] = sy * inv;
        r[i * 3 + 2] = sz * inv;
    }

    float4* op = (float4*)(out + ((size_t)blk * GRID_PTS + h0) * 3);
    op[0] = make_float4(r[0], r[1], r[2],  r[3]);
    op[1] = make_float4(r[4], r[5], r[6],  r[7]);
    op[2] = make_float4(r[8], r[9], r[10], r[11]);
}

extern "C" void kernel_launch(void* const* d_in, const int* in_sizes, int n_in,
                              void* d_out, int out_size, void* d_ws, size_t ws_size,
                              hipStream_t stream) {
    const float4* ctrl  = (const float4*)d_in[0];  // (8, 64, 64, 4) f32
    const int*    uspan = (const int*)d_in[1];     // (512)
    const int*    vspan = (const int*)d_in[2];     // (512)
    const float4* Nu    = (const float4*)d_in[3];  // (512, 4) f32
    const float4* Nv    = (const float4*)d_in[4];  // (512, 4) f32
    float*        out   = (float*)d_out;           // (8, 512, 512, 3) f32

    const int blocks = 8 * GRID_PTS;  // one per (b, g)
    surfeval_kernel<<<blocks, 128, 0, stream>>>(ctrl, uspan, vspan, Nu, Nv, out);
}